// Round 13
// baseline (5518.816 us; speedup 1.0000x reference)
//
#include <hip/hip_runtime.h>
#include <math.h>

#define NNODE 1024
#define BATCH 16
#define NB    16384
#define TT    12

typedef __bf16 bf16x8 __attribute__((ext_vector_type(8)));
typedef float  f32x4  __attribute__((ext_vector_type(4)));

static inline int cdiv(int a, int b) { return (a + b - 1) / b; }

// proper s_waitcnt immediate: vmcnt N (6-bit split [3:0],[15:14]), lgkm=15, exp=7
__host__ __device__ constexpr int vmenc(int n) {
    return 0x0F70 | (n & 0xF) | ((n >> 4) << 14);
}

// async global->LDS, 16B per lane, wave-uniform LDS base + lane*16
__device__ inline void gll16(const void* g, void* l) {
    __builtin_amdgcn_global_load_lds(
        (const __attribute__((address_space(1))) void*)g,
        (__attribute__((address_space(3))) void*)l, 16, 0, 0);
}

// ---------------------------------------------------------------------------
// Split-bf16 GEMM, counted-vmcnt double-buffered pipeline, BK-templated,
// coalesced staging (1KB chunks), XCD-chunked block swizzle.
// D[i][j] = sum_k A[i][k]*B[j][k]  (both k-contig).
// PA/PB: plane counts (1 = hi only). Passes: Ah*Bh always; Ah*Bl if PB==2;
//        Al*Bh if PA==2 && kt<K3 && bn<aloCols.
// LDS swizzle: 16B slot s at global row R stored at slot s^(R&(NSLOT-1));
// applied on the global source address (write) and the ds_read slot (read).
// Since R = lrow (mod 16) for fragment reads and NSLOT<=16, read term is
// lrow&(NSLOT-1). (Round-12 bug: write side used only R mod RPC.)
// EPI 0: plain bf16 store Ch
// EPI 1: +bias, sigmoid -> Cf
// EPI 2: RM-transposed hop store: RM[(n*16+b)*ldc + (1+bn/1024)*cpad + i] (hi)
// EPI 3: +bias, tanh, fused GRU: hout = r*hout + (1-r)*hc  (r from zrp)
// ---------------------------------------------------------------------------
template<int BM, int BN, int BK, int PA, int PB, int EPI>
__global__ __launch_bounds__(256) void mm_kern(
    const __bf16* __restrict__ Ah, const __bf16* __restrict__ Al, long lda, long zA,
    const __bf16* __restrict__ Bh, const __bf16* __restrict__ Bl, long zB, long ldb,
    int M, int Ksteps, int K3, int aloCols,
    __bf16* __restrict__ Ch, float* __restrict__ Cf,
    long ldc, long zC, int cpadParam, long MoffParam,
    const float* __restrict__ bias, const float* __restrict__ zrp,
    float* __restrict__ hout)
{
    constexpr int WM = BM / 2, WN = BN / 2;
    constexpr int MF = WM / 16, NF = WN / 16;
    constexpr int NSLOT = BK / 8;                   // 16B slots per row
    constexpr int RPC = 512 / BK;                   // rows per 1KB chunk
    constexpr int nA = BM / RPC, nB = BN / RPC;     // chunks per plane
    constexpr int nAl = (PA == 2) ? nA : 0;
    constexpr int nBl = (PB == 2) ? nB : 0;
    constexpr int TOT = nA + nAl + nB + nBl;
    constexpr int NPS = TOT / 4;                    // chunks per wave
    constexpr int cAlw = nAl / 4;
    constexpr int NPfull = NPS, NPnoAl = NPS - cAlw;
    constexpr int e0 = nA, e1 = nA + nAl, e2 = nA + nAl + nB;
    constexpr int bAl = BM * BK;
    constexpr int bBh = (PA == 2 ? 2 : 1) * BM * BK;
    constexpr int bBl = bBh + BN * BK;
    constexpr int BUFE = ((PA == 2 ? 2 : 1) * BM + (PB == 2 ? 2 : 1) * BN) * BK;
    __shared__ __bf16 smem[2 * BUFE];

    // ---- block swizzle: bijective XCD chunking + 2-col band ----
    const int nwgx = gridDim.x, nwgy = gridDim.y;
    const int nwg = nwgx * nwgy;
    const int lin = blockIdx.y * nwgx + blockIdx.x;
    const int q8 = nwg >> 3, r8 = nwg & 7;
    const int xcd = lin & 7, cidx = lin >> 3;
    const int lin2 = (xcd < r8) ? (xcd * (q8 + 1) + cidx)
                                : (r8 * (q8 + 1) + (xcd - r8) * q8 + cidx);
    const int G = ((nwgx & 1) == 0) ? 2 : 1;
    const int band = G * nwgy;
    const int gb = lin2 / band, rm = lin2 - gb * band;
    const int bxs = gb * G + (rm & (G - 1));
    const int bys = rm / G;

    const int bm = bys * BM, bn = bxs * BN;
    const int tid = threadIdx.x, w = tid >> 6, lane = tid & 63;
    const int wr = w >> 1, wc = w & 1;
    const int lgrp = lane >> 4, lrow = lane & 15;
    const bool aloNeed = (PA == 2) && (bn < aloCols);

    Ah += (size_t)blockIdx.z * zA;  Al += (size_t)blockIdx.z * zA;
    Bh += (size_t)blockIdx.z * zB;  Bl += (size_t)blockIdx.z * zB;

    // staging: lane -> row-in-chunk = lane/NSLOT; global slot for lane l at
    // global row R = (l & (NSLOT-1)) ^ (R & (NSLOT-1))  [write-side swizzle]
    const int srow = lane / NSLOT;
    const __bf16* sp[NPS];
    int dpo[NPS];
    int ttyp[NPS];
#pragma unroll
    for (int p = 0; p < NPS; ++p) {
        int q = p * 4 + w;
        int tile = (q < e0) ? 0 : (q < e1) ? 1 : (q < e2) ? 2 : 3;
        int qq = q - ((tile == 0) ? 0 : (tile == 1) ? e0 : (tile == 2) ? e1 : e2);
        const __bf16* base = (tile == 0) ? Ah : (tile == 1) ? Al : (tile == 2) ? Bh : Bl;
        long ld = (tile < 2) ? lda : ldb;
        int  rb = (tile < 2) ? bm : bn;
        int rr = qq * RPC + srow;                       // row within tile
        int sl = ((lane & (NSLOT - 1)) ^ (rr & (NSLOT - 1))) * 8;
        sp[p] = base + (size_t)(rb + rr) * ld + sl;
        int tbase = (tile == 0) ? 0 : (tile == 1) ? bAl : (tile == 2) ? bBh : bBl;
        dpo[p] = tbase * 2 + qq * 1024;
        ttyp[p] = tile;
    }

    f32x4 acc[MF][NF];
#pragma unroll
    for (int i = 0; i < MF; ++i)
#pragma unroll
        for (int j = 0; j < NF; ++j)
#pragma unroll
            for (int e = 0; e < 4; ++e) acc[i][j][e] = 0.f;

    auto stage = [&](int kt, int bsel) {
        char* lb = (char*)smem + bsel * (BUFE * 2);
#pragma unroll
        for (int p = 0; p < NPS; ++p) {
            int tile = ttyp[p];
            bool go = (tile == 0) || (tile == 2)
                   || (tile == 1 && aloNeed && kt < K3)
                   || (tile == 3 && PB == 2);
            if (go) gll16(sp[p] + (size_t)kt * BK, lb + dpo[p]);
        }
    };

    stage(0, 0);

    const int rsw = (lrow & (NSLOT - 1));   // read-side row-swizzle term

    for (int kt = 0; kt < Ksteps; ++kt) {
        const int cur = kt & 1;
        __builtin_amdgcn_s_barrier();
        __builtin_amdgcn_sched_barrier(0);
        if (kt + 1 < Ksteps) {
            stage(kt + 1, cur ^ 1);
            if (aloNeed && (kt + 1) < K3)
                __builtin_amdgcn_s_waitcnt(vmenc(NPfull));
            else
                __builtin_amdgcn_s_waitcnt(vmenc(NPnoAl));
        } else {
            __builtin_amdgcn_s_waitcnt(vmenc(0));
        }
        __builtin_amdgcn_s_barrier();
        __builtin_amdgcn_sched_barrier(0);

        const __bf16* sb = smem + cur * BUFE;
#pragma unroll
        for (int kh = 0; kh < BK / 32; ++kh) {
            const int so = (((kh * 4 + lgrp) ^ rsw) & (NSLOT - 1)) * 8;
            bf16x8 aH[MF], bHf[NF];
#pragma unroll
            for (int mf = 0; mf < MF; ++mf) {
                int row = wr * WM + mf * 16 + lrow;
                aH[mf] = *(const bf16x8*)(sb + (size_t)row * BK + so);
            }
#pragma unroll
            for (int nf = 0; nf < NF; ++nf) {
                int col = wc * WN + nf * 16 + lrow;
                bHf[nf] = *(const bf16x8*)(sb + bBh + (size_t)col * BK + so);
            }
            __builtin_amdgcn_s_setprio(1);
#pragma unroll
            for (int mf = 0; mf < MF; ++mf)
#pragma unroll
                for (int nf = 0; nf < NF; ++nf)
                    acc[mf][nf] = __builtin_amdgcn_mfma_f32_16x16x32_bf16(aH[mf], bHf[nf], acc[mf][nf], 0, 0, 0);

            if (PB == 2) {
                bf16x8 bLf[NF];
#pragma unroll
                for (int nf = 0; nf < NF; ++nf) {
                    int col = wc * WN + nf * 16 + lrow;
                    bLf[nf] = *(const bf16x8*)(sb + bBl + (size_t)col * BK + so);
                }
#pragma unroll
                for (int mf = 0; mf < MF; ++mf)
#pragma unroll
                    for (int nf = 0; nf < NF; ++nf)
                        acc[mf][nf] = __builtin_amdgcn_mfma_f32_16x16x32_bf16(aH[mf], bLf[nf], acc[mf][nf], 0, 0, 0);
            }
            if (PA == 2 && aloNeed && kt < K3) {
                bf16x8 aL[MF];
#pragma unroll
                for (int mf = 0; mf < MF; ++mf) {
                    int row = wr * WM + mf * 16 + lrow;
                    aL[mf] = *(const bf16x8*)(sb + bAl + (size_t)row * BK + so);
                }
#pragma unroll
                for (int mf = 0; mf < MF; ++mf)
#pragma unroll
                    for (int nf = 0; nf < NF; ++nf)
                        acc[mf][nf] = __builtin_amdgcn_mfma_f32_16x16x32_bf16(aL[mf], bHf[nf], acc[mf][nf], 0, 0, 0);
            }
            __builtin_amdgcn_s_setprio(0);
        }
    }

    if (EPI == 2) {
        // ---- LDS-transposed RM store (hi only) ----
        constexpr int NI = BM / 16;
        __syncthreads();
        __bf16* LT = smem;                  // BM*BN elems <= 2*BUFE
#pragma unroll
        for (int mf = 0; mf < MF; ++mf) {
            int il = wr * MF + mf;
#pragma unroll
            for (int nf = 0; nf < NF; ++nf) {
                int nl = wc * WN + nf * 16 + lrow;
#pragma unroll
                for (int r = 0; r < 4; ++r) {
                    int b = lgrp * 4 + r;
                    LT[nl * BM + ((b ^ (nl & 15)) * NI) + il] = (__bf16)acc[mf][nf][r];
                }
            }
        }
        __syncthreads();
        const int ibase = (int)((MoffParam + bm) >> 4);
        const long scol = (long)(1 + (bn >> 10)) * cpadParam + ibase;
        const bool fullM = (bm + BM <= M);
        const bool al16 = ((scol & 7) == 0) && (NI == 8);
#pragma unroll
        for (int q = 0; q < (BN * 16) / 256; ++q) {
            int rr = q * 256 + tid;
            int nl = rr >> 4, b = rr & 15;
            int el = nl * BM + ((b ^ (nl & 15)) * NI);
            int n = (bn & 1023) + nl;
            size_t addr = ((size_t)n * 16 + b) * ldc + scol;
            if (fullM && al16) {
                *(uint4*)(Ch + addr) = *(const uint4*)(LT + el);
            } else {
#pragma unroll
                for (int il = 0; il < NI; ++il)
                    if (bm + il * 16 + b < M) Ch[addr + il] = LT[el + il];
            }
        }
        return;
    }

    const size_t cz = (size_t)blockIdx.z * zC;
#pragma unroll
    for (int mf = 0; mf < MF; ++mf) {
        int gi0 = bm + wr * WM + mf * 16 + lgrp * 4;
#pragma unroll
        for (int nf = 0; nf < NF; ++nf) {
            int gj = bn + wc * WN + nf * 16 + lrow;
#pragma unroll
            for (int r = 0; r < 4; ++r) {
                int gi = gi0 + r;
                if (gi < M) {
                    float v = acc[mf][nf][r];
                    if (EPI == 0) {
                        Ch[cz + (size_t)gi * ldc + gj] = (__bf16)v;
                    } else if (EPI == 1) {
                        v += bias[gj];
                        v = 1.f / (1.f + expf(-v));
                        Cf[cz + (size_t)gi * ldc + gj] = v;
                    } else if (EPI == 3) {
                        v += bias[gj];
                        v = tanhf(v);
                        float rg = zrp[(size_t)gi * 2 * ldc + ldc + gj];
                        size_t hix = (size_t)gi * ldc + gj;
                        hout[hix] = rg * hout[hix] + (1.f - rg) * v;
                    }
                }
            }
        }
    }
}

// ---------------------------------------------------------------------------
// Fused concat-build + transpose: computes v(cc,n,b), writes RM hi plane
// (coalesced, cc-contig) and T hi plane (coalesced, n-contig, via LDS)
// for cc in [cc0, C).
// ---------------------------------------------------------------------------
template<int MODE>
__global__ __launch_bounds__(256) void xcatT_kern(
    __bf16* __restrict__ RMh, __bf16* __restrict__ Th,
    const float* __restrict__ s1, const float* __restrict__ s2,
    const float* __restrict__ h, const float* __restrict__ zr,
    int t, int cc0, int KP)
{
    constexpr int C = (MODE < 2) ? 65 : (MODE < 4) ? 128 : (MODE < 6) ? 130 : 256;
    __shared__ __bf16 tile[32][66];
    const int b = blockIdx.z, nt = blockIdx.y * 64;
    const int kkb = cc0 + blockIdx.x * 32;
    const int tdx = threadIdx.x;

#pragma unroll
    for (int rep = 0; rep < 8; ++rep) {
        int cc = kkb + (tdx & 31);
        int nl = rep * 8 + (tdx >> 5);
        int n = nt + nl;
        int r = n * 16 + b;
        float v = 0.f;
        if (cc < C) {
            if (MODE == 0 || MODE == 1) {
                if (cc == 0) v = s1[((size_t)b * TT + t) * NNODE + n];
                else { float hv = h[(size_t)r * 64 + cc - 1];
                       v = (MODE == 1) ? zr[(size_t)r * 128 + cc - 1] * hv : hv; }
            } else if (MODE == 2 || MODE == 3) {
                if (cc < 64) v = s1[(size_t)r * 64 + cc];
                else { float hv = h[(size_t)r * 64 + cc - 64];
                       v = (MODE == 3) ? zr[(size_t)r * 128 + cc - 64] * hv : hv; }
            } else if (MODE == 4 || MODE == 5) {
                if (cc == 0) v = s1[r];
                else if (cc == 1) v = s2[((size_t)b * TT + t) * NNODE + n];
                else { float hv = h[(size_t)r * 128 + cc - 2];
                       v = (MODE == 5) ? zr[(size_t)r * 256 + cc - 2] * hv : hv; }
            } else {
                if (cc < 128) v = s1[(size_t)r * 128 + cc];
                else { float hv = h[(size_t)r * 128 + cc - 128];
                       v = (MODE == 7) ? zr[(size_t)r * 256 + cc - 128] * hv : hv; }
            }
        }
        __bf16 hi = (__bf16)v;
        if (cc < C)
            RMh[(size_t)r * KP + cc] = hi;
        tile[tdx & 31][nl] = hi;
    }
    __syncthreads();
#pragma unroll
    for (int rep = 0; rep < 8; ++rep) {
        int kkl = rep * 4 + (tdx >> 6);
        int kk = kkb + kkl;
        int n = nt + (tdx & 63);
        if (kk < C)
            Th[((size_t)kk * 16 + b) * 1024 + n] = tile[kkl][tdx & 63];
    }
}

// ---------------------------------------------------------------------------
// small kernels
// ---------------------------------------------------------------------------
__global__ __launch_bounds__(256) void compute_ne(
    const float* __restrict__ We1, const float* __restrict__ We2,
    const float* __restrict__ Mem, float* __restrict__ ne1, float* __restrict__ ne2)
{
    int idx = blockIdx.x * 256 + threadIdx.x;
    if (idx >= 2 * 65536) return;
    int which = idx >> 16;
    int i = idx & 65535;
    int n = i >> 6, d = i & 63;
    const float* We = which ? We2 : We1;
    float acc = 0.f;
#pragma unroll
    for (int k = 0; k < 20; ++k) acc += We[n * 20 + k] * Mem[k * 64 + d];
    (which ? ne2 : ne1)[i] = acc;
}

__global__ __launch_bounds__(256) void build_g(
    const float* __restrict__ ne1, const float* __restrict__ ne2, float* __restrict__ g)
{
    int row = blockIdx.x;
    int n = row & 1023;
    const float* qa = (row < 1024) ? ne1 : ne2;
    const float* kb = (row < 1024) ? ne2 : ne1;
    __shared__ float q[64];
    __shared__ float sc[1024];
    __shared__ float red[256];
    int tid = threadIdx.x;
    if (tid < 64) q[tid] = qa[n * 64 + tid];
    __syncthreads();
    for (int m = tid; m < 1024; m += 256) {
        float acc = 0.f;
        const float* kr = kb + m * 64;
#pragma unroll 8
        for (int d = 0; d < 64; ++d) acc += q[d] * kr[d];
        sc[m] = fmaxf(acc, 0.f);
    }
    __syncthreads();
    float mx = -1e30f;
    for (int m = tid; m < 1024; m += 256) mx = fmaxf(mx, sc[m]);
    red[tid] = mx;
    __syncthreads();
    for (int s2 = 128; s2 > 0; s2 >>= 1) {
        if (tid < s2) red[tid] = fmaxf(red[tid], red[tid + s2]);
        __syncthreads();
    }
    mx = red[0];
    __syncthreads();
    float sum = 0.f;
    for (int m = tid; m < 1024; m += 256) {
        float e = expf(sc[m] - mx);
        sc[m] = e;
        sum += e;
    }
    red[tid] = sum;
    __syncthreads();
    for (int s2 = 128; s2 > 0; s2 >>= 1) {
        if (tid < s2) red[tid] += red[tid + s2];
        __syncthreads();
    }
    float inv = 1.f / red[0];
    for (int m = tid; m < 1024; m += 256) g[(size_t)row * 1024 + m] = sc[m] * inv;
}

__global__ __launch_bounds__(256) void g_split(
    const float* __restrict__ g, __bf16* __restrict__ gh, __bf16* __restrict__ gl)
{
    int i = blockIdx.x * 256 + threadIdx.x;
    if (i >= 2048 * 1024) return;
    float v = g[i];
    __bf16 h = (__bf16)v;
    gh[i] = h;
    gl[i] = (__bf16)(v - (float)h);
}

__global__ __launch_bounds__(256) void gT_kern(
    const float* __restrict__ gf, __bf16* __restrict__ gTh, __bf16* __restrict__ gTl)
{
    __shared__ float tile[32][33];
    int z = blockIdx.z;
    int m0 = blockIdx.y * 32, k0 = blockIdx.x * 32;
    int tx = threadIdx.x & 31, ty = threadIdx.x >> 5;
    for (int r = ty; r < 32; r += 8)
        tile[r][tx] = gf[(size_t)(z * 1024 + m0 + r) * 1024 + k0 + tx];
    __syncthreads();
    for (int r = ty; r < 32; r += 8) {
        float v = tile[tx][r];
        __bf16 h = (__bf16)v;
        size_t o = (size_t)(z * 1024 + k0 + r) * 1024 + m0 + tx;
        gTh[o] = h;
        gTl[o] = (__bf16)(v - (float)h);
    }
}

// effective weight, transposed [cout][KP], padded slots (cpad), hi plane only
__global__ __launch_bounds__(256) void build_weffT(
    const float* __restrict__ W, __bf16* __restrict__ dh,
    int c, int cpad, int cout, int KP)
{
    int idx = blockIdx.x * 256 + threadIdx.x;
    if (idx >= cout * KP) return;
    int o = idx / KP, kk = idx - o * KP;
    float v = 0.f;
    if (kk < 5 * cpad) {
        int s = kk / cpad;
        int i = kk - s * cpad;
        if (i < c) {
            if      (s == 0) v = W[(size_t)(0 * c + i) * cout + o] + W[(size_t)(3 * c + i) * cout + o]
                               - W[(size_t)(2 * c + i) * cout + o] - W[(size_t)(5 * c + i) * cout + o];
            else if (s == 1) v = W[(size_t)(1 * c + i) * cout + o];
            else if (s == 2) v = W[(size_t)(4 * c + i) * cout + o];
            else if (s == 3) v = 2.f * W[(size_t)(2 * c + i) * cout + o];
            else             v = 2.f * W[(size_t)(5 * c + i) * cout + o];
        }
    }
    dh[idx] = (__bf16)v;
}

// attention; writes htc (=dh0 state) AND dh1 copy (fused init)
__global__ __launch_bounds__(64) void attention(
    const float* __restrict__ h, const float* __restrict__ Wq,
    const float* __restrict__ Mem, float* __restrict__ htc, float* __restrict__ htc2)
{
    int r = blockIdx.x;
    int j = threadIdx.x;
    __shared__ float hr[64], q[64], sc[20];
    hr[j] = h[(size_t)r * 64 + j];
    __syncthreads();
    float acc = 0.f;
#pragma unroll 8
    for (int i = 0; i < 64; ++i) acc += hr[i] * Wq[i * 64 + j];
    q[j] = acc;
    __syncthreads();
    if (j < 20) {
        float a = 0.f;
#pragma unroll 8
        for (int d = 0; d < 64; ++d) a += q[d] * Mem[j * 64 + d];
        sc[j] = a;
    }
    __syncthreads();
    if (j == 0) {
        float mx = sc[0];
        for (int m = 1; m < 20; ++m) mx = fmaxf(mx, sc[m]);
        float s = 0.f;
        for (int m = 0; m < 20; ++m) { sc[m] = expf(sc[m] - mx); s += sc[m]; }
        float inv = 1.f / s;
        for (int m = 0; m < 20; ++m) sc[m] *= inv;
    }
    __syncthreads();
    float v = 0.f;
#pragma unroll
    for (int m = 0; m < 20; ++m) v += sc[m] * Mem[m * 64 + j];
    htc[(size_t)r * 128 + j] = hr[j];
    htc[(size_t)r * 128 + 64 + j] = v;
    htc2[(size_t)r * 128 + j] = hr[j];
    htc2[(size_t)r * 128 + 64 + j] = v;
}

__global__ __launch_bounds__(256) void proj_out(
    const float* __restrict__ h1, const float* __restrict__ pw, const float* __restrict__ pb,
    float* __restrict__ go, float* __restrict__ out, int t)
{
    int r = blockIdx.x * 256 + threadIdx.x;
    if (r >= NB) return;
    float acc = pb[0];
    const float* hr = h1 + (size_t)r * 128;
#pragma unroll 8
    for (int i = 0; i < 128; ++i) acc += hr[i] * pw[i];
    go[r] = acc;
    int n = r >> 4, b = r & 15;
    out[((size_t)b * TT + t) * NNODE + n] = acc;
}

// ---------------------------------------------------------------------------
// host
// ---------------------------------------------------------------------------
extern "C" void kernel_launch(void* const* d_in, const int* in_sizes, int n_in,
                              void* d_out, int out_size, void* d_ws, size_t ws_size,
                              hipStream_t stream)
{
    const float* x      = (const float*)d_in[0];
    const float* y_cov  = (const float*)d_in[1];
    const float* Memory = (const float*)d_in[2];
    const float* Wq     = (const float*)d_in[3];
    const float* We1    = (const float*)d_in[4];
    const float* We2    = (const float*)d_in[5];
    const float* e0gw = (const float*)d_in[6];  const float* e0gb = (const float*)d_in[7];
    const float* e0uw = (const float*)d_in[8];  const float* e0ub = (const float*)d_in[9];
    const float* e1gw = (const float*)d_in[10]; const float* e1gb = (const float*)d_in[11];
    const float* e1uw = (const float*)d_in[12]; const float* e1ub = (const float*)d_in[13];
    const float* d0gw = (const float*)d_in[14]; const float* d0gb = (const float*)d_in[15];
    const float* d0uw = (const float*)d_in[16]; const float* d0ub = (const float*)d_in[17];
    const float* d1gw = (const float*)d_in[18]; const float* d1gb = (const float*)d_in[19];
    const float* d1uw = (const float*)d_in[20]; const float* d1ub = (const float*)d_in[21];
    const float* proj_w = (const float*)d_in[22];
    const float* proj_b = (const float*)d_in[23];
    float* out = (float*)d_out;
    (void)in_sizes; (void)n_in; (void)out_size; (void)ws_size;

    char* wsb = (char*)d_ws;
    size_t off = 0;
    auto alloc = [&](size_t bytes) -> void* {
        void* p = wsb + off;
        off += (bytes + 255) & ~(size_t)255;
        return p;
    };

    float*  gf    = (float*) alloc(2048L * 1024 * 4);
    __bf16* gquad = (__bf16*)alloc(4096L * 1024 * 2);   // g1|g2|G2_1|G2_2 (hi)
    __bf16* gsL   = (__bf16*)alloc(2048L * 1024 * 2);
    __bf16* gTh   = (__bf16*)alloc(2048L * 1024 * 2);
    __bf16* gTl   = (__bf16*)alloc(2048L * 1024 * 2);
    float*  ne1   = (float*) alloc(65536L * 4);
    float*  ne2   = (float*) alloc(65536L * 4);
    auto allocWT = [&](int cout, int KP) {
        return (__bf16*)alloc((size_t)cout * KP * 2);
    };
    __bf16* wE0g = allocWT(128, 384);   __bf16* wE0u = allocWT(64, 384);
    __bf16* wE1g = allocWT(128, 640);   __bf16* wE1u = allocWT(64, 640);
    __bf16* wD0g = allocWT(256, 768);   __bf16* wD0u = allocWT(128, 768);
    __bf16* wD1g = allocWT(256, 1280);  __bf16* wD1u = allocWT(128, 1280);
    __bf16* RMh = (__bf16*)alloc((size_t)NB * 1280 * 2);
    __bf16* Th  = (__bf16*)alloc((size_t)4096 * 1024 * 2);
    float* zr  = (float*)alloc((size_t)NB * 256 * 4);
    float* h0e = (float*)alloc((size_t)NB * 64 * 4);
    float* h1e = (float*)alloc((size_t)NB * 64 * 4);
    float* dh0 = (float*)alloc((size_t)NB * 128 * 4);
    float* dh1 = (float*)alloc((size_t)NB * 128 * 4);
    float* gob = (float*)alloc((size_t)NB * 4);

    // ---- setup ----
    compute_ne<<<cdiv(2 * 65536, 256), 256, 0, stream>>>(We1, We2, Memory, ne1, ne2);
    build_g<<<2048, 256, 0, stream>>>(ne1, ne2, gf);
    g_split<<<cdiv(2048 * 1024, 256), 256, 0, stream>>>(gf, gquad, gsL);
    {
        dim3 gt(32, 32, 2);
        gT_kern<<<gt, 256, 0, stream>>>(gf, gTh, gTl);
        // G2_z = g_z @ g_z  (3-pass split), -> gquad rows 2048 + z*1024
        dim3 gg(8, 8, 2);
        mm_kern<128, 128, 64, 2, 2, 0><<<gg, 256, 0, stream>>>(
            gquad, gsL, 1024, (long)1024 * 1024,
            gTh, gTl, (long)1024 * 1024, 1024,
            1024, 16, 16, 1 << 30,
            gquad + (size_t)2048 * 1024, nullptr, 1024, (long)1024 * 1024,
            0, 0, nullptr, nullptr, nullptr);
    }
    build_weffT<<<cdiv(128 * 384, 256), 256, 0, stream>>>(e0gw, wE0g, 65, 72, 128, 384);
    build_weffT<<<cdiv(64 * 384, 256), 256, 0, stream>>>(e0uw, wE0u, 65, 72, 64, 384);
    build_weffT<<<cdiv(128 * 640, 256), 256, 0, stream>>>(e1gw, wE1g, 128, 128, 128, 640);
    build_weffT<<<cdiv(64 * 640, 256), 256, 0, stream>>>(e1uw, wE1u, 128, 128, 64, 640);
    build_weffT<<<cdiv(256 * 768, 256), 256, 0, stream>>>(d0gw, wD0g, 130, 144, 256, 768);
    build_weffT<<<cdiv(128 * 768, 256), 256, 0, stream>>>(d0uw, wD0u, 130, 144, 128, 768);
    build_weffT<<<cdiv(256 * 1280, 256), 256, 0, stream>>>(d1gw, wD1g, 256, 256, 256, 1280);
    build_weffT<<<cdiv(128 * 1280, 256), 256, 0, stream>>>(d1uw, wD1u, 256, 256, 128, 1280);
    hipMemsetAsync(h0e, 0, (size_t)NB * 64 * 4 * 2, stream);   // h0e + h1e adjacent

    // cell core: hop (EPI2 BK=64) + pure-bf16 weight GEMM (64x64, BK=128)
    auto agcn_core = [&](int c, int cpad, int cin2, int KP,
                         const __bf16* wt, const float* bias, int cout, int epi,
                         float* zrOrOut, float* hptr) {
        int Moff = 16 * cin2, Mv = 16 * c - Moff;
        dim3 gh(32, cdiv(Mv, 128), 1);
        mm_kern<128, 128, 64, 1, 1, 2><<<gh, 256, 0, stream>>>(
            Th + (size_t)Moff * 1024, Th + (size_t)Moff * 1024, 1024, 0,
            gquad, gquad, 0, 1024,
            Mv, 16, 0, 0,
            RMh, nullptr, KP, 0, cpad, Moff,
            nullptr, nullptr, nullptr);
        dim3 gw(cout / 64, 256, 1);
        if (epi == 1) {
            mm_kern<64, 64, 128, 1, 1, 1><<<gw, 256, 0, stream>>>(
                RMh, RMh, KP, 0, wt, wt, 0, KP, NB, KP / 128, 0, 0,
                nullptr, zrOrOut, cout, 0, 0, 0, bias, nullptr, nullptr);
        } else {
            mm_kern<64, 64, 128, 1, 1, 3><<<gw, 256, 0, stream>>>(
                RMh, RMh, KP, 0, wt, wt, 0, KP, NB, KP / 128, 0, 0,
                nullptr, nullptr, cout, 0, 0, 0, bias, zrOrOut, hptr);
        }
    };

    // ---- encoder ----
    for (int t = 0; t < TT; ++t) {
        xcatT_kern<0><<<dim3(3, 16, 16), 256, 0, stream>>>(RMh, Th, x, nullptr, h0e, nullptr, t, 0, 384);
        agcn_core(65, 72, 0, 384, wE0g, e0gb, 128, 1, zr, nullptr);
        xcatT_kern<1><<<dim3(2, 16, 16), 256, 0, stream>>>(RMh, Th, x, nullptr, h0e, zr, t, 1, 384);
        agcn_core(65, 72, 1, 384, wE0u, e0ub, 64, 3, zr, h0e);
        xcatT_kern<2><<<dim3(4, 16, 16), 256, 0, stream>>>(RMh, Th, h0e, nullptr, h1e, nullptr, t, 0, 640);
        agcn_core(128, 128, 0, 640, wE1g, e1gb, 128, 1, zr, nullptr);
        xcatT_kern<3><<<dim3(2, 16, 16), 256, 0, stream>>>(RMh, Th, h0e, nullptr, h1e, zr, t, 64, 640);
        agcn_core(128, 128, 64, 640, wE1u, e1ub, 64, 3, zr, h1e);
    }

    // ---- memory attention (writes dh0 and dh1) ----
    attention<<<NB, 64, 0, stream>>>(h1e, Wq, Memory, dh0, dh1);
    hipMemsetAsync(gob, 0, (size_t)NB * 4, stream);

    // ---- decoder ----
    for (int t = 0; t < TT; ++t) {
        xcatT_kern<4><<<dim3(5, 16, 16), 256, 0, stream>>>(RMh, Th, gob, y_cov, dh0, nullptr, t, 0, 768);
        agcn_core(130, 144, 0, 768, wD0g, d0gb, 256, 1, zr, nullptr);
        xcatT_kern<5><<<dim3(4, 16, 16), 256, 0, stream>>>(RMh, Th, gob, y_cov, dh0, zr, t, 2, 768);
        agcn_core(130, 144, 2, 768, wD0u, d0ub, 128, 3, zr, dh0);
        xcatT_kern<6><<<dim3(8, 16, 16), 256, 0, stream>>>(RMh, Th, dh0, nullptr, dh1, nullptr, t, 0, 1280);
        agcn_core(256, 256, 0, 1280, wD1g, d1gb, 256, 1, zr, nullptr);
        xcatT_kern<7><<<dim3(4, 16, 16), 256, 0, stream>>>(RMh, Th, dh0, nullptr, dh1, zr, t, 128, 1280);
        agcn_core(256, 256, 128, 1280, wD1u, d1ub, 128, 3, zr, dh1);
        proj_out<<<cdiv(NB, 256), 256, 0, stream>>>(dh1, proj_w, proj_b, gob, out, t);
    }
}

// Round 14
// 5286.974 us; speedup vs baseline: 1.0439x; 1.0439x over previous
//
#include <hip/hip_runtime.h>
#include <math.h>

#define NNODE 1024
#define BATCH 16
#define NB    16384
#define TT    12

typedef __bf16 bf16x8 __attribute__((ext_vector_type(8)));
typedef float  f32x4  __attribute__((ext_vector_type(4)));

static inline int cdiv(int a, int b) { return (a + b - 1) / b; }

// proper s_waitcnt immediate: vmcnt N (6-bit split [3:0],[15:14]), lgkm=15, exp=7
__host__ __device__ constexpr int vmenc(int n) {
    return 0x0F70 | (n & 0xF) | ((n >> 4) << 14);
}

// async global->LDS, 16B per lane, wave-uniform LDS base + lane*16
__device__ inline void gll16(const void* g, void* l) {
    __builtin_amdgcn_global_load_lds(
        (const __attribute__((address_space(1))) void*)g,
        (__attribute__((address_space(3))) void*)l, 16, 0, 0);
}

// ---------------------------------------------------------------------------
// Split-bf16 GEMM, counted-vmcnt double-buffered pipeline, BK-templated,
// coalesced staging (1KB chunks), XCD-chunked block swizzle.
// D[i][j] = sum_k A[i][k]*B[j][k]  (both k-contig).
// PA/PB: plane counts (1 = hi only). Passes: Ah*Bh always; Ah*Bl if PB==2;
//        Al*Bh if PA==2 && kt<K3 && bn<aloCols.
// LDS swizzle: 16B slot s at global row R stored at slot s^(R&(NSLOT-1));
// applied on the global source address (write) and the ds_read slot (read).
// EPI 0: plain bf16 store Ch
// EPI 1: +bias, sigmoid -> Cf
// EPI 2: RM-transposed hop store: RM[(n*16+b)*ldc + (1+bn/1024)*cpad + i] (hi)
// EPI 3: +bias, tanh, fused GRU: hout = r*hout + (1-r)*hc  (r from zrp)
// ---------------------------------------------------------------------------
template<int BM, int BN, int BK, int PA, int PB, int EPI>
__global__ __launch_bounds__(256) void mm_kern(
    const __bf16* __restrict__ Ah, const __bf16* __restrict__ Al, long lda, long zA,
    const __bf16* __restrict__ Bh, const __bf16* __restrict__ Bl, long zB, long ldb,
    int M, int Ksteps, int K3, int aloCols,
    __bf16* __restrict__ Ch, float* __restrict__ Cf,
    long ldc, long zC, int cpadParam, long MoffParam,
    const float* __restrict__ bias, const float* __restrict__ zrp,
    float* __restrict__ hout)
{
    constexpr int WM = BM / 2, WN = BN / 2;
    constexpr int MF = WM / 16, NF = WN / 16;
    constexpr int NSLOT = BK / 8;                   // 16B slots per row
    constexpr int RPC = 512 / BK;                   // rows per 1KB chunk
    constexpr int nA = BM / RPC, nB = BN / RPC;     // chunks per plane
    constexpr int nAl = (PA == 2) ? nA : 0;
    constexpr int nBl = (PB == 2) ? nB : 0;
    constexpr int TOT = nA + nAl + nB + nBl;
    constexpr int NPS = TOT / 4;                    // chunks per wave
    constexpr int cAlw = nAl / 4;
    constexpr int NPfull = NPS, NPnoAl = NPS - cAlw;
    constexpr int e0 = nA, e1 = nA + nAl, e2 = nA + nAl + nB;
    constexpr int bAl = BM * BK;
    constexpr int bBh = (PA == 2 ? 2 : 1) * BM * BK;
    constexpr int bBl = bBh + BN * BK;
    constexpr int BUFE = ((PA == 2 ? 2 : 1) * BM + (PB == 2 ? 2 : 1) * BN) * BK;
    __shared__ __bf16 smem[2 * BUFE];

    // ---- block swizzle: bijective XCD chunking + 2-col band ----
    const int nwgx = gridDim.x, nwgy = gridDim.y;
    const int nwg = nwgx * nwgy;
    const int lin = blockIdx.y * nwgx + blockIdx.x;
    const int q8 = nwg >> 3, r8 = nwg & 7;
    const int xcd = lin & 7, cidx = lin >> 3;
    const int lin2 = (xcd < r8) ? (xcd * (q8 + 1) + cidx)
                                : (r8 * (q8 + 1) + (xcd - r8) * q8 + cidx);
    const int G = ((nwgx & 1) == 0) ? 2 : 1;
    const int band = G * nwgy;
    const int gb = lin2 / band, rm = lin2 - gb * band;
    const int bxs = gb * G + (rm & (G - 1));
    const int bys = rm / G;

    const int bm = bys * BM, bn = bxs * BN;
    const int tid = threadIdx.x, w = tid >> 6, lane = tid & 63;
    const int wr = w >> 1, wc = w & 1;
    const int lgrp = lane >> 4, lrow = lane & 15;
    const bool aloNeed = (PA == 2) && (bn < aloCols);

    Ah += (size_t)blockIdx.z * zA;  Al += (size_t)blockIdx.z * zA;
    Bh += (size_t)blockIdx.z * zB;  Bl += (size_t)blockIdx.z * zB;

    // staging: lane -> row-in-chunk = lane/NSLOT; global slot for lane l at
    // global row R = (l & (NSLOT-1)) ^ (R & (NSLOT-1))  [write-side swizzle]
    const int srow = lane / NSLOT;
    const __bf16* sp[NPS];
    int dpo[NPS];
    int ttyp[NPS];
#pragma unroll
    for (int p = 0; p < NPS; ++p) {
        int q = p * 4 + w;
        int tile = (q < e0) ? 0 : (q < e1) ? 1 : (q < e2) ? 2 : 3;
        int qq = q - ((tile == 0) ? 0 : (tile == 1) ? e0 : (tile == 2) ? e1 : e2);
        const __bf16* base = (tile == 0) ? Ah : (tile == 1) ? Al : (tile == 2) ? Bh : Bl;
        long ld = (tile < 2) ? lda : ldb;
        int  rb = (tile < 2) ? bm : bn;
        int rr = qq * RPC + srow;                       // row within tile
        int sl = ((lane & (NSLOT - 1)) ^ (rr & (NSLOT - 1))) * 8;
        sp[p] = base + (size_t)(rb + rr) * ld + sl;
        int tbase = (tile == 0) ? 0 : (tile == 1) ? bAl : (tile == 2) ? bBh : bBl;
        dpo[p] = tbase * 2 + qq * 1024;
        ttyp[p] = tile;
    }

    f32x4 acc[MF][NF];
#pragma unroll
    for (int i = 0; i < MF; ++i)
#pragma unroll
        for (int j = 0; j < NF; ++j)
#pragma unroll
            for (int e = 0; e < 4; ++e) acc[i][j][e] = 0.f;

    auto stage = [&](int kt, int bsel) {
        char* lb = (char*)smem + bsel * (BUFE * 2);
#pragma unroll
        for (int p = 0; p < NPS; ++p) {
            int tile = ttyp[p];
            bool go = (tile == 0) || (tile == 2)
                   || (tile == 1 && aloNeed && kt < K3)
                   || (tile == 3 && PB == 2);
            if (go) gll16(sp[p] + (size_t)kt * BK, lb + dpo[p]);
        }
    };

    stage(0, 0);

    const int rsw = (lrow & (NSLOT - 1));   // read-side row-swizzle term

    for (int kt = 0; kt < Ksteps; ++kt) {
        const int cur = kt & 1;
        __builtin_amdgcn_s_barrier();
        __builtin_amdgcn_sched_barrier(0);
        if (kt + 1 < Ksteps) {
            stage(kt + 1, cur ^ 1);
            if (aloNeed && (kt + 1) < K3)
                __builtin_amdgcn_s_waitcnt(vmenc(NPfull));
            else
                __builtin_amdgcn_s_waitcnt(vmenc(NPnoAl));
        } else {
            __builtin_amdgcn_s_waitcnt(vmenc(0));
        }
        __builtin_amdgcn_s_barrier();
        __builtin_amdgcn_sched_barrier(0);

        const __bf16* sb = smem + cur * BUFE;
#pragma unroll
        for (int kh = 0; kh < BK / 32; ++kh) {
            const int so = (((kh * 4 + lgrp) ^ rsw) & (NSLOT - 1)) * 8;
            bf16x8 aH[MF], bHf[NF];
#pragma unroll
            for (int mf = 0; mf < MF; ++mf) {
                int row = wr * WM + mf * 16 + lrow;
                aH[mf] = *(const bf16x8*)(sb + (size_t)row * BK + so);
            }
#pragma unroll
            for (int nf = 0; nf < NF; ++nf) {
                int col = wc * WN + nf * 16 + lrow;
                bHf[nf] = *(const bf16x8*)(sb + bBh + (size_t)col * BK + so);
            }
            __builtin_amdgcn_s_setprio(1);
#pragma unroll
            for (int mf = 0; mf < MF; ++mf)
#pragma unroll
                for (int nf = 0; nf < NF; ++nf)
                    acc[mf][nf] = __builtin_amdgcn_mfma_f32_16x16x32_bf16(aH[mf], bHf[nf], acc[mf][nf], 0, 0, 0);

            if (PB == 2) {
                bf16x8 bLf[NF];
#pragma unroll
                for (int nf = 0; nf < NF; ++nf) {
                    int col = wc * WN + nf * 16 + lrow;
                    bLf[nf] = *(const bf16x8*)(sb + bBl + (size_t)col * BK + so);
                }
#pragma unroll
                for (int mf = 0; mf < MF; ++mf)
#pragma unroll
                    for (int nf = 0; nf < NF; ++nf)
                        acc[mf][nf] = __builtin_amdgcn_mfma_f32_16x16x32_bf16(aH[mf], bLf[nf], acc[mf][nf], 0, 0, 0);
            }
            if (PA == 2 && aloNeed && kt < K3) {
                bf16x8 aL[MF];
#pragma unroll
                for (int mf = 0; mf < MF; ++mf) {
                    int row = wr * WM + mf * 16 + lrow;
                    aL[mf] = *(const bf16x8*)(sb + bAl + (size_t)row * BK + so);
                }
#pragma unroll
                for (int mf = 0; mf < MF; ++mf)
#pragma unroll
                    for (int nf = 0; nf < NF; ++nf)
                        acc[mf][nf] = __builtin_amdgcn_mfma_f32_16x16x32_bf16(aL[mf], bHf[nf], acc[mf][nf], 0, 0, 0);
            }
            __builtin_amdgcn_s_setprio(0);
        }
    }

    if (EPI == 2) {
        // ---- LDS-transposed RM store (hi only) ----
        constexpr int NI = BM / 16;
        __syncthreads();
        __bf16* LT = smem;                  // BM*BN elems <= 2*BUFE
#pragma unroll
        for (int mf = 0; mf < MF; ++mf) {
            int il = wr * MF + mf;
#pragma unroll
            for (int nf = 0; nf < NF; ++nf) {
                int nl = wc * WN + nf * 16 + lrow;
#pragma unroll
                for (int r = 0; r < 4; ++r) {
                    int b = lgrp * 4 + r;
                    LT[nl * BM + ((b ^ (nl & 15)) * NI) + il] = (__bf16)acc[mf][nf][r];
                }
            }
        }
        __syncthreads();
        const int ibase = (int)((MoffParam + bm) >> 4);
        const long scol = (long)(1 + (bn >> 10)) * cpadParam + ibase;
        const bool fullM = (bm + BM <= M);
        const bool al16 = ((scol & 7) == 0) && (NI == 8);
#pragma unroll
        for (int q = 0; q < (BN * 16) / 256; ++q) {
            int rr = q * 256 + tid;
            int nl = rr >> 4, b = rr & 15;
            int el = nl * BM + ((b ^ (nl & 15)) * NI);
            int n = (bn & 1023) + nl;
            size_t addr = ((size_t)n * 16 + b) * ldc + scol;
            if (fullM && al16) {
                *(uint4*)(Ch + addr) = *(const uint4*)(LT + el);
            } else {
#pragma unroll
                for (int il = 0; il < NI; ++il)
                    if (bm + il * 16 + b < M) Ch[addr + il] = LT[el + il];
            }
        }
        return;
    }

    const size_t cz = (size_t)blockIdx.z * zC;
#pragma unroll
    for (int mf = 0; mf < MF; ++mf) {
        int gi0 = bm + wr * WM + mf * 16 + lgrp * 4;
#pragma unroll
        for (int nf = 0; nf < NF; ++nf) {
            int gj = bn + wc * WN + nf * 16 + lrow;
#pragma unroll
            for (int r = 0; r < 4; ++r) {
                int gi = gi0 + r;
                if (gi < M) {
                    float v = acc[mf][nf][r];
                    if (EPI == 0) {
                        Ch[cz + (size_t)gi * ldc + gj] = (__bf16)v;
                    } else if (EPI == 1) {
                        v += bias[gj];
                        v = 1.f / (1.f + expf(-v));
                        Cf[cz + (size_t)gi * ldc + gj] = v;
                    } else if (EPI == 3) {
                        v += bias[gj];
                        v = tanhf(v);
                        float rg = zrp[(size_t)gi * 2 * ldc + ldc + gj];
                        size_t hix = (size_t)gi * ldc + gj;
                        hout[hix] = rg * hout[hix] + (1.f - rg) * v;
                    }
                }
            }
        }
    }
}

// ---------------------------------------------------------------------------
// Fused concat-build + transpose: computes v(cc,n,b), writes RM hi plane
// (coalesced, cc-contig) and T hi plane (coalesced, n-contig, via LDS)
// for cc in [cc0, C).
// ---------------------------------------------------------------------------
template<int MODE>
__global__ __launch_bounds__(256) void xcatT_kern(
    __bf16* __restrict__ RMh, __bf16* __restrict__ Th,
    const float* __restrict__ s1, const float* __restrict__ s2,
    const float* __restrict__ h, const float* __restrict__ zr,
    int t, int cc0, int KP)
{
    constexpr int C = (MODE < 2) ? 65 : (MODE < 4) ? 128 : (MODE < 6) ? 130 : 256;
    __shared__ __bf16 tile[32][66];
    const int b = blockIdx.z, nt = blockIdx.y * 64;
    const int kkb = cc0 + blockIdx.x * 32;
    const int tdx = threadIdx.x;

#pragma unroll
    for (int rep = 0; rep < 8; ++rep) {
        int cc = kkb + (tdx & 31);
        int nl = rep * 8 + (tdx >> 5);
        int n = nt + nl;
        int r = n * 16 + b;
        float v = 0.f;
        if (cc < C) {
            if (MODE == 0 || MODE == 1) {
                if (cc == 0) v = s1[((size_t)b * TT + t) * NNODE + n];
                else { float hv = h[(size_t)r * 64 + cc - 1];
                       v = (MODE == 1) ? zr[(size_t)r * 128 + cc - 1] * hv : hv; }
            } else if (MODE == 2 || MODE == 3) {
                if (cc < 64) v = s1[(size_t)r * 64 + cc];
                else { float hv = h[(size_t)r * 64 + cc - 64];
                       v = (MODE == 3) ? zr[(size_t)r * 128 + cc - 64] * hv : hv; }
            } else if (MODE == 4 || MODE == 5) {
                if (cc == 0) v = s1[r];
                else if (cc == 1) v = s2[((size_t)b * TT + t) * NNODE + n];
                else { float hv = h[(size_t)r * 128 + cc - 2];
                       v = (MODE == 5) ? zr[(size_t)r * 256 + cc - 2] * hv : hv; }
            } else {
                if (cc < 128) v = s1[(size_t)r * 128 + cc];
                else { float hv = h[(size_t)r * 128 + cc - 128];
                       v = (MODE == 7) ? zr[(size_t)r * 256 + cc - 128] * hv : hv; }
            }
        }
        __bf16 hi = (__bf16)v;
        if (cc < C)
            RMh[(size_t)r * KP + cc] = hi;
        tile[tdx & 31][nl] = hi;
    }
    __syncthreads();
#pragma unroll
    for (int rep = 0; rep < 8; ++rep) {
        int kkl = rep * 4 + (tdx >> 6);
        int kk = kkb + kkl;
        int n = nt + (tdx & 63);
        if (kk < C)
            Th[((size_t)kk * 16 + b) * 1024 + n] = tile[kkl][tdx & 63];
    }
}

// ---------------------------------------------------------------------------
// small kernels
// ---------------------------------------------------------------------------
__global__ __launch_bounds__(256) void compute_ne(
    const float* __restrict__ We1, const float* __restrict__ We2,
    const float* __restrict__ Mem, float* __restrict__ ne1, float* __restrict__ ne2)
{
    int idx = blockIdx.x * 256 + threadIdx.x;
    if (idx >= 2 * 65536) return;
    int which = idx >> 16;
    int i = idx & 65535;
    int n = i >> 6, d = i & 63;
    const float* We = which ? We2 : We1;
    float acc = 0.f;
#pragma unroll
    for (int k = 0; k < 20; ++k) acc += We[n * 20 + k] * Mem[k * 64 + d];
    (which ? ne2 : ne1)[i] = acc;
}

__global__ __launch_bounds__(256) void build_g(
    const float* __restrict__ ne1, const float* __restrict__ ne2, float* __restrict__ g)
{
    int row = blockIdx.x;
    int n = row & 1023;
    const float* qa = (row < 1024) ? ne1 : ne2;
    const float* kb = (row < 1024) ? ne2 : ne1;
    __shared__ float q[64];
    __shared__ float sc[1024];
    __shared__ float red[256];
    int tid = threadIdx.x;
    if (tid < 64) q[tid] = qa[n * 64 + tid];
    __syncthreads();
    for (int m = tid; m < 1024; m += 256) {
        float acc = 0.f;
        const float* kr = kb + m * 64;
#pragma unroll 8
        for (int d = 0; d < 64; ++d) acc += q[d] * kr[d];
        sc[m] = fmaxf(acc, 0.f);
    }
    __syncthreads();
    float mx = -1e30f;
    for (int m = tid; m < 1024; m += 256) mx = fmaxf(mx, sc[m]);
    red[tid] = mx;
    __syncthreads();
    for (int s2 = 128; s2 > 0; s2 >>= 1) {
        if (tid < s2) red[tid] = fmaxf(red[tid], red[tid + s2]);
        __syncthreads();
    }
    mx = red[0];
    __syncthreads();
    float sum = 0.f;
    for (int m = tid; m < 1024; m += 256) {
        float e = expf(sc[m] - mx);
        sc[m] = e;
        sum += e;
    }
    red[tid] = sum;
    __syncthreads();
    for (int s2 = 128; s2 > 0; s2 >>= 1) {
        if (tid < s2) red[tid] += red[tid + s2];
        __syncthreads();
    }
    float inv = 1.f / red[0];
    for (int m = tid; m < 1024; m += 256) g[(size_t)row * 1024 + m] = sc[m] * inv;
}

__global__ __launch_bounds__(256) void g_split(
    const float* __restrict__ g, __bf16* __restrict__ gh, __bf16* __restrict__ gl)
{
    int i = blockIdx.x * 256 + threadIdx.x;
    if (i >= 2048 * 1024) return;
    float v = g[i];
    __bf16 h = (__bf16)v;
    gh[i] = h;
    gl[i] = (__bf16)(v - (float)h);
}

__global__ __launch_bounds__(256) void gT_kern(
    const float* __restrict__ gf, __bf16* __restrict__ gTh, __bf16* __restrict__ gTl)
{
    __shared__ float tile[32][33];
    int z = blockIdx.z;
    int m0 = blockIdx.y * 32, k0 = blockIdx.x * 32;
    int tx = threadIdx.x & 31, ty = threadIdx.x >> 5;
    for (int r = ty; r < 32; r += 8)
        tile[r][tx] = gf[(size_t)(z * 1024 + m0 + r) * 1024 + k0 + tx];
    __syncthreads();
    for (int r = ty; r < 32; r += 8) {
        float v = tile[tx][r];
        __bf16 h = (__bf16)v;
        size_t o = (size_t)(z * 1024 + k0 + r) * 1024 + m0 + tx;
        gTh[o] = h;
        gTl[o] = (__bf16)(v - (float)h);
    }
}

// effective weight, transposed [cout][KP], padded slots (cpad), hi plane only
__global__ __launch_bounds__(256) void build_weffT(
    const float* __restrict__ W, __bf16* __restrict__ dh,
    int c, int cpad, int cout, int KP)
{
    int idx = blockIdx.x * 256 + threadIdx.x;
    if (idx >= cout * KP) return;
    int o = idx / KP, kk = idx - o * KP;
    float v = 0.f;
    if (kk < 5 * cpad) {
        int s = kk / cpad;
        int i = kk - s * cpad;
        if (i < c) {
            if      (s == 0) v = W[(size_t)(0 * c + i) * cout + o] + W[(size_t)(3 * c + i) * cout + o]
                               - W[(size_t)(2 * c + i) * cout + o] - W[(size_t)(5 * c + i) * cout + o];
            else if (s == 1) v = W[(size_t)(1 * c + i) * cout + o];
            else if (s == 2) v = W[(size_t)(4 * c + i) * cout + o];
            else if (s == 3) v = 2.f * W[(size_t)(2 * c + i) * cout + o];
            else             v = 2.f * W[(size_t)(5 * c + i) * cout + o];
        }
    }
    dh[idx] = (__bf16)v;
}

// attention; writes htc (=dh0 state) AND dh1 copy (fused init)
__global__ __launch_bounds__(64) void attention(
    const float* __restrict__ h, const float* __restrict__ Wq,
    const float* __restrict__ Mem, float* __restrict__ htc, float* __restrict__ htc2)
{
    int r = blockIdx.x;
    int j = threadIdx.x;
    __shared__ float hr[64], q[64], sc[20];
    hr[j] = h[(size_t)r * 64 + j];
    __syncthreads();
    float acc = 0.f;
#pragma unroll 8
    for (int i = 0; i < 64; ++i) acc += hr[i] * Wq[i * 64 + j];
    q[j] = acc;
    __syncthreads();
    if (j < 20) {
        float a = 0.f;
#pragma unroll 8
        for (int d = 0; d < 64; ++d) a += q[d] * Mem[j * 64 + d];
        sc[j] = a;
    }
    __syncthreads();
    if (j == 0) {
        float mx = sc[0];
        for (int m = 1; m < 20; ++m) mx = fmaxf(mx, sc[m]);
        float s = 0.f;
        for (int m = 0; m < 20; ++m) { sc[m] = expf(sc[m] - mx); s += sc[m]; }
        float inv = 1.f / s;
        for (int m = 0; m < 20; ++m) sc[m] *= inv;
    }
    __syncthreads();
    float v = 0.f;
#pragma unroll
    for (int m = 0; m < 20; ++m) v += sc[m] * Mem[m * 64 + j];
    htc[(size_t)r * 128 + j] = hr[j];
    htc[(size_t)r * 128 + 64 + j] = v;
    htc2[(size_t)r * 128 + j] = hr[j];
    htc2[(size_t)r * 128 + 64 + j] = v;
}

__global__ __launch_bounds__(256) void proj_out(
    const float* __restrict__ h1, const float* __restrict__ pw, const float* __restrict__ pb,
    float* __restrict__ go, float* __restrict__ out, int t)
{
    int r = blockIdx.x * 256 + threadIdx.x;
    if (r >= NB) return;
    float acc = pb[0];
    const float* hr = h1 + (size_t)r * 128;
#pragma unroll 8
    for (int i = 0; i < 128; ++i) acc += hr[i] * pw[i];
    go[r] = acc;
    int n = r >> 4, b = r & 15;
    out[((size_t)b * TT + t) * NNODE + n] = acc;
}

// ---------------------------------------------------------------------------
// host
// ---------------------------------------------------------------------------
extern "C" void kernel_launch(void* const* d_in, const int* in_sizes, int n_in,
                              void* d_out, int out_size, void* d_ws, size_t ws_size,
                              hipStream_t stream)
{
    const float* x      = (const float*)d_in[0];
    const float* y_cov  = (const float*)d_in[1];
    const float* Memory = (const float*)d_in[2];
    const float* Wq     = (const float*)d_in[3];
    const float* We1    = (const float*)d_in[4];
    const float* We2    = (const float*)d_in[5];
    const float* e0gw = (const float*)d_in[6];  const float* e0gb = (const float*)d_in[7];
    const float* e0uw = (const float*)d_in[8];  const float* e0ub = (const float*)d_in[9];
    const float* e1gw = (const float*)d_in[10]; const float* e1gb = (const float*)d_in[11];
    const float* e1uw = (const float*)d_in[12]; const float* e1ub = (const float*)d_in[13];
    const float* d0gw = (const float*)d_in[14]; const float* d0gb = (const float*)d_in[15];
    const float* d0uw = (const float*)d_in[16]; const float* d0ub = (const float*)d_in[17];
    const float* d1gw = (const float*)d_in[18]; const float* d1gb = (const float*)d_in[19];
    const float* d1uw = (const float*)d_in[20]; const float* d1ub = (const float*)d_in[21];
    const float* proj_w = (const float*)d_in[22];
    const float* proj_b = (const float*)d_in[23];
    float* out = (float*)d_out;
    (void)in_sizes; (void)n_in; (void)out_size; (void)ws_size;

    char* wsb = (char*)d_ws;
    size_t off = 0;
    auto alloc = [&](size_t bytes) -> void* {
        void* p = wsb + off;
        off += (bytes + 255) & ~(size_t)255;
        return p;
    };

    float*  gf    = (float*) alloc(2048L * 1024 * 4);
    __bf16* gquad = (__bf16*)alloc(4096L * 1024 * 2);   // g1|g2|G2_1|G2_2 (hi)
    __bf16* gsL   = (__bf16*)alloc(2048L * 1024 * 2);
    __bf16* gTh   = (__bf16*)alloc(2048L * 1024 * 2);
    __bf16* gTl   = (__bf16*)alloc(2048L * 1024 * 2);
    float*  ne1   = (float*) alloc(65536L * 4);
    float*  ne2   = (float*) alloc(65536L * 4);
    auto allocWT = [&](int cout, int KP) {
        return (__bf16*)alloc((size_t)cout * KP * 2);
    };
    __bf16* wE0g = allocWT(128, 384);   __bf16* wE0u = allocWT(64, 384);
    __bf16* wE1g = allocWT(128, 640);   __bf16* wE1u = allocWT(64, 640);
    __bf16* wD0g = allocWT(256, 704);   __bf16* wD0u = allocWT(128, 704);
    __bf16* wD1g = allocWT(256, 1280);  __bf16* wD1u = allocWT(128, 1280);
    __bf16* RMh = (__bf16*)alloc((size_t)NB * 1280 * 2);
    __bf16* Th  = (__bf16*)alloc((size_t)4096 * 1024 * 2);
    float* zr  = (float*)alloc((size_t)NB * 256 * 4);
    float* h0e = (float*)alloc((size_t)NB * 64 * 4);
    float* h1e = (float*)alloc((size_t)NB * 64 * 4);
    float* dh0 = (float*)alloc((size_t)NB * 128 * 4);
    float* dh1 = (float*)alloc((size_t)NB * 128 * 4);
    float* gob = (float*)alloc((size_t)NB * 4);

    // ---- setup ----
    compute_ne<<<cdiv(2 * 65536, 256), 256, 0, stream>>>(We1, We2, Memory, ne1, ne2);
    build_g<<<2048, 256, 0, stream>>>(ne1, ne2, gf);
    g_split<<<cdiv(2048 * 1024, 256), 256, 0, stream>>>(gf, gquad, gsL);
    {
        dim3 gt(32, 32, 2);
        gT_kern<<<gt, 256, 0, stream>>>(gf, gTh, gTl);
        // G2_z = g_z @ g_z  (3-pass split), -> gquad rows 2048 + z*1024
        dim3 gg(8, 8, 2);
        mm_kern<128, 128, 64, 2, 2, 0><<<gg, 256, 0, stream>>>(
            gquad, gsL, 1024, (long)1024 * 1024,
            gTh, gTl, (long)1024 * 1024, 1024,
            1024, 16, 16, 1 << 30,
            gquad + (size_t)2048 * 1024, nullptr, 1024, (long)1024 * 1024,
            0, 0, nullptr, nullptr, nullptr);
    }
    build_weffT<<<cdiv(128 * 384, 256), 256, 0, stream>>>(e0gw, wE0g, 65, 72, 128, 384);
    build_weffT<<<cdiv(64 * 384, 256), 256, 0, stream>>>(e0uw, wE0u, 65, 72, 64, 384);
    build_weffT<<<cdiv(128 * 640, 256), 256, 0, stream>>>(e1gw, wE1g, 128, 128, 128, 640);
    build_weffT<<<cdiv(64 * 640, 256), 256, 0, stream>>>(e1uw, wE1u, 128, 128, 64, 640);
    build_weffT<<<cdiv(256 * 704, 256), 256, 0, stream>>>(d0gw, wD0g, 130, 136, 256, 704);
    build_weffT<<<cdiv(128 * 704, 256), 256, 0, stream>>>(d0uw, wD0u, 130, 136, 128, 704);
    build_weffT<<<cdiv(256 * 1280, 256), 256, 0, stream>>>(d1gw, wD1g, 256, 256, 256, 1280);
    build_weffT<<<cdiv(128 * 1280, 256), 256, 0, stream>>>(d1uw, wD1u, 256, 256, 128, 1280);
    hipMemsetAsync(h0e, 0, (size_t)NB * 64 * 4 * 2, stream);   // h0e + h1e adjacent

    // cell core: hop (EPI2 BK=64) + pure-bf16 weight GEMM (BK=64, BM=64)
    auto agcn_core = [&](int c, int cpad, int cin2, int KP,
                         const __bf16* wt, const float* bias, int cout, int epi,
                         float* zrOrOut, float* hptr) {
        int Moff = 16 * cin2, Mv = 16 * c - Moff;
        dim3 gh(32, cdiv(Mv, 128), 1);
        mm_kern<128, 128, 64, 1, 1, 2><<<gh, 256, 0, stream>>>(
            Th + (size_t)Moff * 1024, Th + (size_t)Moff * 1024, 1024, 0,
            gquad, gquad, 0, 1024,
            Mv, 16, 0, 0,
            RMh, nullptr, KP, 0, cpad, Moff,
            nullptr, nullptr, nullptr);
        if (epi == 1) {
            if (cout == 256) {
                dim3 gw(2, 256, 1);
                mm_kern<64, 128, 64, 1, 1, 1><<<gw, 256, 0, stream>>>(
                    RMh, RMh, KP, 0, wt, wt, 0, KP, NB, KP / 64, 0, 0,
                    nullptr, zrOrOut, cout, 0, 0, 0, bias, nullptr, nullptr);
            } else {
                dim3 gw(2, 256, 1);
                mm_kern<64, 64, 64, 1, 1, 1><<<gw, 256, 0, stream>>>(
                    RMh, RMh, KP, 0, wt, wt, 0, KP, NB, KP / 64, 0, 0,
                    nullptr, zrOrOut, cout, 0, 0, 0, bias, nullptr, nullptr);
            }
        } else {
            if (cout == 64) {
                dim3 gw(1, 256, 1);
                mm_kern<64, 64, 64, 1, 1, 3><<<gw, 256, 0, stream>>>(
                    RMh, RMh, KP, 0, wt, wt, 0, KP, NB, KP / 64, 0, 0,
                    nullptr, nullptr, cout, 0, 0, 0, bias, zrOrOut, hptr);
            } else {
                dim3 gw(2, 256, 1);
                mm_kern<64, 64, 64, 1, 1, 3><<<gw, 256, 0, stream>>>(
                    RMh, RMh, KP, 0, wt, wt, 0, KP, NB, KP / 64, 0, 0,
                    nullptr, nullptr, cout, 0, 0, 0, bias, zrOrOut, hptr);
            }
        }
    };

    // ---- encoder ----
    for (int t = 0; t < TT; ++t) {
        xcatT_kern<0><<<dim3(3, 16, 16), 256, 0, stream>>>(RMh, Th, x, nullptr, h0e, nullptr, t, 0, 384);
        agcn_core(65, 72, 0, 384, wE0g, e0gb, 128, 1, zr, nullptr);
        xcatT_kern<1><<<dim3(2, 16, 16), 256, 0, stream>>>(RMh, Th, x, nullptr, h0e, zr, t, 1, 384);
        agcn_core(65, 72, 1, 384, wE0u, e0ub, 64, 3, zr, h0e);
        xcatT_kern<2><<<dim3(4, 16, 16), 256, 0, stream>>>(RMh, Th, h0e, nullptr, h1e, nullptr, t, 0, 640);
        agcn_core(128, 128, 0, 640, wE1g, e1gb, 128, 1, zr, nullptr);
        xcatT_kern<3><<<dim3(2, 16, 16), 256, 0, stream>>>(RMh, Th, h0e, nullptr, h1e, zr, t, 64, 640);
        agcn_core(128, 128, 64, 640, wE1u, e1ub, 64, 3, zr, h1e);
    }

    // ---- memory attention (writes dh0 and dh1) ----
    attention<<<NB, 64, 0, stream>>>(h1e, Wq, Memory, dh0, dh1);
    hipMemsetAsync(gob, 0, (size_t)NB * 4, stream);

    // ---- decoder ----
    for (int t = 0; t < TT; ++t) {
        xcatT_kern<4><<<dim3(5, 16, 16), 256, 0, stream>>>(RMh, Th, gob, y_cov, dh0, nullptr, t, 0, 704);
        agcn_core(130, 136, 0, 704, wD0g, d0gb, 256, 1, zr, nullptr);
        xcatT_kern<5><<<dim3(4, 16, 16), 256, 0, stream>>>(RMh, Th, gob, y_cov, dh0, zr, t, 2, 704);
        agcn_core(130, 136, 2, 704, wD0u, d0ub, 128, 3, zr, dh0);
        xcatT_kern<6><<<dim3(8, 16, 16), 256, 0, stream>>>(RMh, Th, dh0, nullptr, dh1, nullptr, t, 0, 1280);
        agcn_core(256, 256, 0, 1280, wD1g, d1gb, 256, 1, zr, nullptr);
        xcatT_kern<7><<<dim3(4, 16, 16), 256, 0, stream>>>(RMh, Th, dh0, nullptr, dh1, zr, t, 128, 1280);
        agcn_core(256, 256, 128, 1280, wD1u, d1ub, 128, 3, zr, dh1);
        proj_out<<<cdiv(NB, 256), 256, 0, stream>>>(dh1, proj_w, proj_b, gob, out, t);
    }
}